// Round 8
// baseline (230.182 us; speedup 1.0000x reference)
//
#include <hip/hip_runtime.h>

// Problem constants
#define EMB  4096
#define DH   128      // QKV_DIM
#define NH   32       // N_HEADS
#define NTOK 16384    // B*S
#define NCOL 384      // qs | k | v columns

// GEMM tile: 64x128 block, BK=64, 2 waves (1x2), wave tile 64x64 (acc 4x4)
#define BM 64
#define BN 128
#define BK 64

typedef __attribute__((ext_vector_type(8))) short short8;
typedef __attribute__((ext_vector_type(4))) short short4_t;
typedef __attribute__((ext_vector_type(4))) float f32x4;

// f32 pair -> packed bf16x2, RNE (hardware cvt)
static __device__ __forceinline__ unsigned int cvt2(float a, float b) {
    unsigned int r;
    asm volatile("v_cvt_pk_bf16_f32 %0, %1, %2" : "=v"(r) : "v"(a), "v"(b));
    return r;
}
// scalar f32 -> bf16 bits, RNE (prep_w only)
static __device__ __forceinline__ unsigned short f2bf(float f) {
    unsigned int u = __builtin_bit_cast(unsigned int, f);
    u += 0x7fffu + ((u >> 16) & 1u);
    return (unsigned short)(u >> 16);
}
// async global->LDS, 16B per lane; LDS dest = wave-uniform base + lane*16
static __device__ __forceinline__ void gload_lds16(const void* g, void* l) {
    __builtin_amdgcn_global_load_lds(
        (const __attribute__((address_space(1))) unsigned int*)g,
        (__attribute__((address_space(3))) unsigned int*)l, 16, 0, 0);
}

// ---------------------------------------------------------------------------
// Kernel 1: build W3B — combined weights W3[384][4096] (bf16), stored as
// 64x64 tiles in gload_lds-linear order with the XOR-chunk swizzle
// PRE-APPLIED, so GEMM B-staging is 8 contiguous 1-KB reads per tile.
//   byte(n,D) = p*524288 + kt*8192 + (r>>3)*1024 + l*16 + (D&7)*2
//   where p=n>>6, r=n&63, kt=D>>6, c_src=(D>>3)&7, l=(r&7)*8 + (c_src^(r&7)).
// Also bias[384].
// ---------------------------------------------------------------------------
__global__ void prep_w(const float* __restrict__ Wq, const float* __restrict__ bq,
                       const float* __restrict__ Wk, const float* __restrict__ bk,
                       const float* __restrict__ Wv, const float* __restrict__ bv,
                       unsigned short* __restrict__ W3B, float* __restrict__ bias) {
    const int tid = blockIdx.x * 256 + threadIdx.x;   // [0, 384*512)
    const int n  = tid >> 9;          // output column [0,384)
    const int ck = tid & 511;         // 8-element chunk of the 4096 K dim
    const int D0 = ck * 8;

    float v[8];
    if (n < DH) {
#pragma unroll
        for (int e = 0; e < 8; ++e) {
            const float4* p = (const float4*)(Wq + (size_t)(D0 + e) * (DH * NH) + n * NH);
            float s = 0.f;
#pragma unroll
            for (int i = 0; i < 8; ++i) { float4 q = p[i]; s += (q.x + q.y) + (q.z + q.w); }
            v[e] = s;
        }
    } else if (n < 2 * DH) {
#pragma unroll
        for (int e = 0; e < 8; ++e) v[e] = Wk[(size_t)(D0 + e) * DH + (n - DH)];
    } else {
#pragma unroll
        for (int e = 0; e < 8; ++e) v[e] = Wv[(size_t)(D0 + e) * DH + (n - 2 * DH)];
    }

    union { short8 s; unsigned int u[4]; } pk;
#pragma unroll
    for (int j = 0; j < 4; ++j)
        pk.u[j] = (unsigned int)f2bf(v[2 * j]) | ((unsigned int)f2bf(v[2 * j + 1]) << 16);

    const int p  = n >> 6, r = n & 63;
    const int kt = ck >> 3, cs = ck & 7;
    const int l  = ((r & 7) << 3) | (cs ^ (r & 7));
    char* dst = (char*)W3B + (size_t)p * 524288 + (size_t)kt * 8192 + (r >> 3) * 1024 + l * 16;
    *(short8*)dst = pk.s;

    if (ck == 0) {
        float b;
        if (n < DH) {
            float s = 0.f;
#pragma unroll
            for (int h = 0; h < NH; ++h) s += bq[n * NH + h];
            b = s;
        } else if (n < 2 * DH) {
            b = bk[n - DH];
        } else {
            b = bv[n - 2 * DH];
        }
        bias[n] = b;
    }
}

// ---------------------------------------------------------------------------
// Kernel 2: qkv_partial[ks] = x[:, ks-half] @ W3[ks-half, :]
// T3+T4 pipeline: double-buffered LDS, raw s_barrier with COUNTED vmcnt(8) —
// loads stay in flight across the barrier, never drained to 0 in the loop.
// VMEM issue ledger (groups of exactly 8 ops, clamped dummies keep it exact):
//   iter t top: outstanding = av_next(8, x for tile t+2)
//   body: WRITE_A(t+1<-av_cur); STAGE_B(t+1)(+8); LOAD_AV(t+3->av_cur)(+8);
//         COMPUTE(t); vmcnt(8) [retires av_next + B(t+1)]; lgkm(0); barrier.
// Buffer safety: each LDS region's last reader is barrier-separated from its
// next writer; Asm/Bsm regions disjoint.
// ---------------------------------------------------------------------------
__global__ __launch_bounds__(128) void gemm_qkv(const float* __restrict__ X,
                         const unsigned short* __restrict__ W3B,
                         float* __restrict__ qkvp, int nsplit) {
    __shared__ __align__(16) unsigned short Asm0[BM * BK];   //  8 KB
    __shared__ __align__(16) unsigned short Asm1[BM * BK];
    __shared__ __align__(16) unsigned short Bsm0[BN * BK];   // 16 KB
    __shared__ __align__(16) unsigned short Bsm1[BN * BK];

    // XCD-bijective remap over 768*nsplit blocks (divisible by 8)
    const int nblk  = 768 * nsplit;
    const int chnk  = nblk >> 3;
    const int bid   = blockIdx.x;
    const int wkid  = (bid & 7) * chnk + (bid >> 3);
    const int ks    = wkid / 768;
    const int rem   = wkid - ks * 768;
    const int my    = rem / 3;                // N fastest: 3 N-tiles adjacent
    const int mx    = rem - my * 3;
    const int m0 = my * BM;
    const int klen = EMB / nsplit;
    const int koff = ks * klen;
    const int nt   = klen / BK;               // 32 (split) or 64
    const int ntm1 = nt - 1;

    const int t = threadIdx.x, lane = t & 63, w = t >> 6;   // w in {0,1}
    const int lmod = lane & 15, lgrp = lane >> 4;

    f32x4 acc[4][4] = {};

    // A: wave w stages rows [w*32, w*32+32); instr i covers rows w*32+i*4+(lane>>4),
    // 16 B at byte offset (lane&15)*16 of the row's 256-B k-span.
    const int arow4 = (lane >> 4);
    const float* xp = X + (size_t)(m0 + w * 32 + arow4) * EMB + koff + (lane & 15) * 4;
    const int acs = (lane & 15) >> 1;
    const int ah4 = (lane & 1) * 4;

    // B: pre-tiled source, panel p = mx*2 + w
    const char* wsrc = (const char*)W3B + (size_t)(mx * 2 + w) * 524288 + ((size_t)koff >> 6) * 8192 + lane * 16;

    float4 avA[8], avB[8];

#define LOAD_AV(T, AV) do { \
    const int tc_ = (T) < ntm1 ? (T) : ntm1; \
    _Pragma("unroll") \
    for (int i = 0; i < 8; ++i) AV[i] = *(const float4*)(xp + tc_ * BK + i * 4 * EMB); \
} while (0)

#define STAGE_B(T, BUF) do { \
    const int tc_ = (T) < ntm1 ? (T) : ntm1; \
    unsigned short* bd = &(BUF)[(w * 64) * BK]; \
    const char* bs = wsrc + (size_t)tc_ * 8192; \
    _Pragma("unroll") \
    for (int i8 = 0; i8 < 8; ++i8) gload_lds16(bs + i8 * 1024, bd + i8 * 8 * BK); \
} while (0)

#define WRITE_A(AV, BUF) do { \
    _Pragma("unroll") \
    for (int idx = 0; idx < 8; ++idx) { \
        const int rl = w * 32 + idx * 4 + arow4; \
        union { short4_t s; unsigned int u[2]; } pk; \
        pk.u[0] = cvt2(AV[idx].x, AV[idx].y); \
        pk.u[1] = cvt2(AV[idx].z, AV[idx].w); \
        *(short4_t*)(&(BUF)[rl * BK + ((acs ^ (rl & 7)) << 3) + ah4]) = pk.s; \
    } \
} while (0)

#define COMPUTE(AB, BB) do { \
    _Pragma("unroll") \
    for (int kh = 0; kh < 2; ++kh) { \
        const int cs = ((kh * 4 + lgrp) ^ (lmod & 7)) * 8; \
        short8 af[4], bf[4]; \
        _Pragma("unroll") \
        for (int i = 0; i < 4; ++i) \
            af[i] = *(const short8*)(&(AB)[(i * 16 + lmod) * BK + cs]); \
        _Pragma("unroll") \
        for (int j = 0; j < 4; ++j) \
            bf[j] = *(const short8*)(&(BB)[(w * 64 + j * 16 + lmod) * BK + cs]); \
        _Pragma("unroll") \
        for (int i = 0; i < 4; ++i) \
            _Pragma("unroll") \
            for (int j = 0; j < 4; ++j) \
                acc[i][j] = __builtin_amdgcn_mfma_f32_16x16x32_bf16(af[i], bf[j], acc[i][j], 0, 0, 0); \
    } \
} while (0)

// counted-vmcnt barrier: keep N vmem groups in flight across it
#define PIPE_BARRIER(N) do { \
    asm volatile("s_waitcnt vmcnt(" #N ")" ::: "memory"); \
    asm volatile("s_waitcnt lgkmcnt(0)" ::: "memory"); \
    __builtin_amdgcn_s_barrier(); \
    asm volatile("" ::: "memory"); \
} while (0)

    // ---- prologue: establish iter-0 invariant ----
    LOAD_AV(0, avA);            // vm: avA(x0)
    STAGE_B(0, Bsm0);           // vm: avA, B0
    LOAD_AV(1, avB);            // vm: avA, B0, avB(x1)
    asm volatile("s_waitcnt vmcnt(8)" ::: "memory");   // avA + B0 done
    WRITE_A(avA, Asm0);
    LOAD_AV(2, avA);            // vm: avB(x1), avA(x2)
    PIPE_BARRIER(8);            // retire avB(x1); avA(x2) stays in flight
    // iter-0 top: LDS0 = tile0 complete; av_cur=avB(x1) complete; av_next=avA(x2) in flight

    for (int tb = 0; tb < nt; tb += 2) {
        // --- even iter t=tb: compute buf0, stage tile tb+1 -> buf1, cur=avB ---
        WRITE_A(avB, Asm1);
        STAGE_B(tb + 1, Bsm1);
        LOAD_AV(tb + 3, avB);
        COMPUTE(Asm0, Bsm0);
        PIPE_BARRIER(8);        // retire avA(x tb+2) + B(tb+1); avB(x tb+3) flies
        // --- odd iter t=tb+1: compute buf1, stage tile tb+2 -> buf0, cur=avA ---
        WRITE_A(avA, Asm0);
        STAGE_B(tb + 2, Bsm0);
        LOAD_AV(tb + 4, avA);
        COMPUTE(Asm1, Bsm1);
        PIPE_BARRIER(8);        // retire avB + B(tb+2); avA flies
    }
    asm volatile("s_waitcnt vmcnt(0) lgkmcnt(0)" ::: "memory");  // drain tail dummies

    // epilogue: C/D layout col = lane&15, row = (lane>>4)*4 + reg
    float* outp = qkvp + (size_t)ks * NTOK * NCOL;
    const int n0 = mx * BN;
#pragma unroll
    for (int j = 0; j < 4; ++j) {
        const int gcol = n0 + w * 64 + j * 16 + lmod;
#pragma unroll
        for (int i = 0; i < 4; ++i) {
            const int grow = m0 + i * 16 + (lgrp << 2);
#pragma unroll
            for (int r = 0; r < 4; ++r)
                outp[(size_t)(grow + r) * NCOL + gcol] = acc[i][j][r];
        }
    }
#undef LOAD_AV
#undef STAGE_B
#undef WRITE_A
#undef COMPUTE
#undef PIPE_BARRIER
}

// ---------------------------------------------------------------------------
// Kernel 3: sum split-K partials + bias, per-token rank-1 softmax, broadcast.
// One wave per token, 4 tokens per block.
// ---------------------------------------------------------------------------
__global__ void attn_out(const float* __restrict__ qkv0, const float* __restrict__ qkv1,
                         const float* __restrict__ bias, float* __restrict__ out,
                         int nsplit) {
    __shared__ float kvs[4][DH][2];
    __shared__ float osm[4][DH];
    const int t = threadIdx.x, lane = t & 63, w = t >> 6;
    const int token = blockIdx.x * 4 + w;
    const float* b0 = qkv0 + (size_t)token * NCOL;

    float q0  = b0[lane],       q1  = b0[64 + lane];
    float kk0 = b0[128 + lane], kk1 = b0[192 + lane];
    float vv0 = b0[256 + lane], vv1 = b0[320 + lane];
    if (nsplit == 2) {
        const float* b1 = qkv1 + (size_t)token * NCOL;
        q0  += b1[lane];       q1  += b1[64 + lane];
        kk0 += b1[128 + lane]; kk1 += b1[192 + lane];
        vv0 += b1[256 + lane]; vv1 += b1[320 + lane];
    }
    q0  += bias[lane];       q1  += bias[64 + lane];
    kk0 += bias[128 + lane]; kk1 += bias[192 + lane];
    vv0 += bias[256 + lane]; vv1 += bias[320 + lane];

    kvs[w][lane][0]      = kk0;  kvs[w][lane][1]      = vv0;
    kvs[w][64 + lane][0] = kk1;  kvs[w][64 + lane][1] = vv1;

    float lmax = fmaxf(kk0, kk1), lmin = fminf(kk0, kk1);
#pragma unroll
    for (int off = 32; off; off >>= 1) {
        lmax = fmaxf(lmax, __shfl_xor(lmax, off));
        lmin = fminf(lmin, __shfl_xor(lmin, off));
    }
    __syncthreads();

    const float c  = 0.088388347648318447f * 1.4426950408889634f; // scale * log2(e)
    const float a0 = q0 * c, a1 = q1 * c;
    const float m0 = (a0 >= 0.f) ? a0 * lmax : a0 * lmin;
    const float m1 = (a1 >= 0.f) ? a1 * lmax : a1 * lmin;

    float s00 = 0.f, s01 = 0.f, s10 = 0.f, s11 = 0.f;
#pragma unroll 4
    for (int e = 0; e < DH; ++e) {
        const float2 kv = *(const float2*)&kvs[w][e][0];   // broadcast read
        const float p0 = exp2f(fmaf(a0, kv.x, -m0));
        const float p1 = exp2f(fmaf(a1, kv.x, -m1));
        s00 += p0;  s01 = fmaf(p0, kv.y, s01);
        s10 += p1;  s11 = fmaf(p1, kv.y, s11);
    }
    osm[w][lane]      = s01 / s00;
    osm[w][64 + lane] = s11 / s10;
    __syncthreads();

    float* orow = out + (size_t)token * (DH * NH);
#pragma unroll
    for (int it = 0; it < 16; ++it) {
        const int idx = it * 64 + lane;          // float4 index within the 4096-row
        const float val = osm[w][idx >> 3];      // d = (idx*4)/32
        float4 f4; f4.x = val; f4.y = val; f4.z = val; f4.w = val;
        *(float4*)(orow + idx * 4) = f4;
    }
}

// ---------------------------------------------------------------------------
extern "C" void kernel_launch(void* const* d_in, const int* in_sizes, int n_in,
                              void* d_out, int out_size, void* d_ws, size_t ws_size,
                              hipStream_t stream) {
    const float* x  = (const float*)d_in[0];
    const float* Wq = (const float*)d_in[1];
    const float* bq = (const float*)d_in[2];
    const float* Wk = (const float*)d_in[3];
    const float* bk = (const float*)d_in[4];
    const float* Wv = (const float*)d_in[5];
    const float* bv = (const float*)d_in[6];
    float* out = (float*)d_out;

    char* ws = (char*)d_ws;
    const size_t off_bias = 3145728;                 // W3B: 6*524288
    const size_t off_q0   = off_bias + 4096;
    const size_t off_q1   = off_q0 + (size_t)NTOK * NCOL * 4;
    const size_t need2    = off_q1 + (size_t)NTOK * NCOL * 4;  // 53,481,472 B

    unsigned short* W3B = (unsigned short*)ws;
    float* bias = (float*)(ws + off_bias);
    float* qkv0 = (float*)(ws + off_q0);
    const int nsplit = (ws_size >= need2) ? 2 : 1;
    float* qkv1 = (nsplit == 2) ? (float*)(ws + off_q1) : qkv0;

    prep_w<<<(NCOL * 512) / 256, 256, 0, stream>>>(Wq, bq, Wk, bk, Wv, bv, W3B, bias);
    gemm_qkv<<<768 * nsplit, 128, 0, stream>>>(x, W3B, qkv0, nsplit);
    attn_out<<<NTOK / 4, 256, 0, stream>>>(qkv0, qkv1, bias, out, nsplit);
}